// Round 11
// baseline (11326.772 us; speedup 1.0000x reference)
//
#include <hip/hip_runtime.h>
#include <stdint.h>

#define H_ 1024
#define NG_ 4096   // 4*H

typedef float f32x4 __attribute__((ext_vector_type(4)));
typedef __bf16 bf16x8 __attribute__((ext_vector_type(8)));

__device__ __forceinline__ unsigned short f2bf(float f) {
  union { float f; uint32_t u; } v; v.f = f;
  uint32_t r = v.u + 0x7FFFu + ((v.u >> 16) & 1u);
  return (unsigned short)(r >> 16);
}
__device__ __forceinline__ float bf2f(unsigned short b) {
  union { uint32_t u; float f; } v; v.u = ((uint32_t)b) << 16; return v.f;
}

__device__ __forceinline__ void gload_lds16(const void* g, void* l) {
  __builtin_amdgcn_global_load_lds(
      (const __attribute__((address_space(1))) void*)g,
      (__attribute__((address_space(3))) void*)l, 16, 0, 0);
}

__device__ __forceinline__ float sigm(float x) { return 1.f / (1.f + __expf(-x)); }
__device__ __forceinline__ float tanh_(float x) { return 1.f - 2.f / (__expf(2.f * x) + 1.f); }

// ---------------------------------------------------------------------------
// Weight prep: permute rows r = (j>>4)*64 + gate*16 + (j&15)  (old = gate*H + j)
// so a 64-wide column group holds 16 units x 4 gates, gate index = n-frag index.
// ---------------------------------------------------------------------------
__global__ void prep_w0(const float* __restrict__ Whh0, unsigned short* __restrict__ Wr) {
  int i = (blockIdx.x * 256 + threadIdx.x) * 4;           // over 4096*1024
  int r = i >> 10, k = i & 1023;
  int gate = (r >> 4) & 3;
  int j = ((r >> 6) << 4) + (r & 15);
  const float4 v = *(const float4*)(Whh0 + (size_t)(gate * H_ + j) * H_ + k);
  ushort4 o; o.x = f2bf(v.x); o.y = f2bf(v.y); o.z = f2bf(v.z); o.w = f2bf(v.w);
  *(ushort4*)(Wr + i) = o;
}

__global__ void prep_wcat(const float* __restrict__ Wih1, const float* __restrict__ Whh1,
                          unsigned short* __restrict__ Wr) {
  int i = (blockIdx.x * 256 + threadIdx.x) * 4;           // over 4096*2048
  int r = i >> 11, k = i & 2047;
  int gate = (r >> 4) & 3;
  int j = ((r >> 6) << 4) + (r & 15);
  const float* src = (k < 1024) ? (Wih1 + (size_t)(gate * H_ + j) * H_ + k)
                                : (Whh1 + (size_t)(gate * H_ + j) * H_ + (k - 1024));
  const float4 v = *(const float4*)src;
  ushort4 o; o.x = f2bf(v.x); o.y = f2bf(v.y); o.z = f2bf(v.z); o.w = f2bf(v.w);
  *(ushort4*)(Wr + (size_t)r * 2048 + k) = o;
}

__global__ void prep_small(const float* __restrict__ Wih0,
                           const float* __restrict__ bih0, const float* __restrict__ bhh0,
                           const float* __restrict__ bih1, const float* __restrict__ bhh1,
                           float* __restrict__ bias0r, float* __restrict__ bias1r,
                           float* __restrict__ wi0r) {
  int r = blockIdx.x * 256 + threadIdx.x;                 // over 4096
  int gate = (r >> 4) & 3;
  int j = ((r >> 6) << 4) + (r & 15);
  int old = gate * H_ + j;
  bias0r[r] = bih0[old] + bhh0[old];
  bias1r[r] = bih1[old] + bhh1[old];
  wi0r[r * 2 + 0] = Wih0[old * 2 + 0];
  wi0r[r * 2 + 1] = Wih0[old * 2 + 1];
}

__global__ void prep_state(const float* __restrict__ h, const float* __restrict__ c,
                           unsigned short* __restrict__ h0b, unsigned short* __restrict__ h1b,
                           float* __restrict__ c0, float* __restrict__ c1, int bh) {
  int i = (blockIdx.x * 256 + threadIdx.x) * 4;           // over B*H
  float4 a = *(const float4*)(h + i);
  float4 b = *(const float4*)(h + (size_t)bh + i);
  ushort4 oa; oa.x = f2bf(a.x); oa.y = f2bf(a.y); oa.z = f2bf(a.z); oa.w = f2bf(a.w);
  ushort4 ob; ob.x = f2bf(b.x); ob.y = f2bf(b.y); ob.z = f2bf(b.z); ob.w = f2bf(b.w);
  *(ushort4*)(h0b + i) = oa;
  *(ushort4*)(h1b + i) = ob;
  *(float4*)(c0 + i) = *(const float4*)(c + i);
  *(float4*)(c1 + i) = *(const float4*)(c + (size_t)bh + i);
}

// ---------------------------------------------------------------------------
// Fused GEMM + LSTM cell.  R11: tile 64(M) x 128(N), BK=32, 4 waves (2Mx2N,
// 32x64 each), 2048 blocks -> ~6 blocks/CU co-resident (vs 4 at 128x128).
// Single-buffered LDS (12 KB), XOR swizzle for BK=32 (4 slots/row of 16B):
//   phys slot = logical ^ ((row>>1)&3); stage src col = ((l&3)^((l>>3)&3))*8;
//   read byte off = ((khi ^ ((lane>>1)&3)) * 16.  2-way b128 = free.
// ---------------------------------------------------------------------------
__global__ void __launch_bounds__(256, 6)
lstm_gemm_cell(const unsigned short* __restrict__ A0,
               const unsigned short* __restrict__ A1,
               int Ktot,
               const unsigned short* __restrict__ Bw,
               const float* __restrict__ biasr,
               const float* __restrict__ wi0r,
               const int* __restrict__ xidx,
               int have_x,
               float* __restrict__ Cst,
               unsigned short* __restrict__ Hout) {
  __shared__ unsigned short As[64 * 32];    // 4 KB
  __shared__ unsigned short Bs[128 * 32];   // 8 KB
  const int tid  = threadIdx.x;
  const int lane = tid & 63;
  const int wv   = tid >> 6;
  const int wm   = wv >> 1, wn = wv & 1;
  const int tile_m = blockIdx.y * 64;
  const int tile_n = blockIdx.x * 128;

  f32x4 acc[2][4];
#pragma unroll
  for (int m = 0; m < 2; ++m)
#pragma unroll
    for (int n = 0; n < 4; ++n) acc[m][n] = (f32x4)0.f;

  // staging: chunk = 16 rows x 32 cols (1 KB = one wave-gload).
  // lane l -> row l>>2, phys slot l&3; source logical slot = (l&3)^((l>>3)&3).
  const int lrow16 = lane >> 2;
  const int lk     = (((lane & 3) ^ ((lane >> 3) & 3)) * 8);

  // fragment read geometry
  const int cl  = lane & 15;
  const int khi = lane >> 4;                         // 0..3 (k-position)
  const int ksw = ((khi ^ ((lane >> 1) & 3)) * 16);  // swizzled byte offset

  const int nk = Ktot >> 5;
  for (int kt = 0; kt < nk; ++kt) {
    const int k0 = kt << 5;
    const unsigned short* Ap; int kl;
    if (k0 < 1024) { Ap = A0; kl = k0; } else { Ap = A1; kl = k0 - 1024; }
    // A: 4 chunks, one per wave
    {
      const int row = wv * 16 + lrow16;
      gload_lds16(Ap + (size_t)(tile_m + row) * H_ + kl + lk, (void*)&As[wv * 512]);
    }
    // B: 8 chunks, two per wave
#pragma unroll
    for (int i = 0; i < 2; ++i) {
      const int c2 = wv + i * 4;
      const int row = c2 * 16 + lrow16;
      gload_lds16(Bw + (size_t)(tile_n + row) * Ktot + k0 + lk, (void*)&Bs[c2 * 512]);
    }
    __syncthreads();

    const char* Ab = (const char*)As;
    const char* Bb = (const char*)Bs;
    bf16x8 af[2], bfr[4];
#pragma unroll
    for (int m = 0; m < 2; ++m)
      af[m] = *(const bf16x8*)(Ab + (wm * 32 + m * 16 + cl) * 64 + ksw);
#pragma unroll
    for (int n = 0; n < 4; ++n)
      bfr[n] = *(const bf16x8*)(Bb + (wn * 64 + n * 16 + cl) * 64 + ksw);
#pragma unroll
    for (int m = 0; m < 2; ++m)
#pragma unroll
      for (int n = 0; n < 4; ++n)
        acc[m][n] = __builtin_amdgcn_mfma_f32_16x16x32_bf16(af[m], bfr[n], acc[m][n], 0, 0, 0);
    __syncthreads();
  }

  // ---- epilogue: fused LSTM cell ----
  const int rq = khi * 4;
  const int jgrp = (tile_n >> 6) + wn;
  const int j = jgrp * 16 + cl;
  float bias[4], w0v[4] = {0, 0, 0, 0}, w1v[4] = {0, 0, 0, 0};
#pragma unroll
  for (int n = 0; n < 4; ++n) {
    int colr = tile_n + wn * 64 + n * 16 + cl;
    bias[n] = biasr[colr];
    if (have_x) { w0v[n] = wi0r[colr * 2]; w1v[n] = wi0r[colr * 2 + 1]; }
  }
#pragma unroll
  for (int m = 0; m < 2; ++m) {
#pragma unroll
    for (int q = 0; q < 4; ++q) {
      int row = tile_m + wm * 32 + m * 16 + rq + q;
      float gi = acc[m][0][q] + bias[0];
      float gf = acc[m][1][q] + bias[1];
      float gg = acc[m][2][q] + bias[2];
      float go = acc[m][3][q] + bias[3];
      if (have_x) {
        int x = xidx[row];
        gi += x ? w1v[0] : w0v[0];
        gf += x ? w1v[1] : w0v[1];
        gg += x ? w1v[2] : w0v[2];
        go += x ? w1v[3] : w0v[3];
      }
      size_t off = (size_t)row * H_ + j;
      float cp = Cst[off];
      float cn = sigm(gf) * cp + sigm(gi) * tanh_(gg);
      float hn = sigm(go) * tanh_(cn);
      Cst[off] = cn;
      Hout[off] = f2bf(hn);
    }
  }
}

// ---------------------------------------------------------------------------
// fc head: logits = h1 @ fcW^T + fcb, write out[b,t,:], argmax -> xidx
// ---------------------------------------------------------------------------
__global__ void fc_argmax(const unsigned short* __restrict__ h1,
                          const float* __restrict__ fcW, const float* __restrict__ fcb,
                          float* __restrict__ out, int* __restrict__ xidx,
                          int t, int pred_len) {
  const int lane = threadIdx.x & 63;
  const int wv = threadIdx.x >> 6;
  const int row = blockIdx.x * 4 + wv;
  const unsigned short* hp = h1 + (size_t)row * H_ + lane * 16;
  float d0 = 0.f, d1 = 0.f;
#pragma unroll
  for (int u = 0; u < 2; ++u) {
    ushort4 ha = *(const ushort4*)(hp + u * 8);
    ushort4 hb = *(const ushort4*)(hp + u * 8 + 4);
    float hv[8] = { bf2f(ha.x), bf2f(ha.y), bf2f(ha.z), bf2f(ha.w),
                    bf2f(hb.x), bf2f(hb.y), bf2f(hb.z), bf2f(hb.w) };
#pragma unroll
    for (int e = 0; e < 8; ++e) {
      int k = lane * 16 + u * 8 + e;
      d0 += hv[e] * fcW[k];
      d1 += hv[e] * fcW[H_ + k];
    }
  }
#pragma unroll
  for (int off = 32; off > 0; off >>= 1) {
    d0 += __shfl_xor(d0, off);
    d1 += __shfl_xor(d1, off);
  }
  if (lane == 0) {
    d0 += fcb[0]; d1 += fcb[1];
    size_t o = ((size_t)row * pred_len + t) * 2;
    out[o] = d0; out[o + 1] = d1;
    xidx[row] = (d1 > d0) ? 1 : 0;
  }
}

// ---------------------------------------------------------------------------
extern "C" void kernel_launch(void* const* d_in, const int* in_sizes, int n_in,
                              void* d_out, int out_size, void* d_ws, size_t ws_size,
                              hipStream_t stream) {
  const float* h     = (const float*)d_in[0];
  const float* c     = (const float*)d_in[1];
  const float* Wih0  = (const float*)d_in[2];
  const float* Whh0  = (const float*)d_in[3];
  const float* bih0  = (const float*)d_in[4];
  const float* bhh0  = (const float*)d_in[5];
  const float* Wih1  = (const float*)d_in[6];
  const float* Whh1  = (const float*)d_in[7];
  const float* bih1  = (const float*)d_in[8];
  const float* bhh1  = (const float*)d_in[9];
  const float* fcW   = (const float*)d_in[10];
  const float* fcb   = (const float*)d_in[11];

  const int B = in_sizes[0] / (2 * H_);           // 4096
  const int pred_len = out_size / (B * 2);        // 64
  const int BH = B * H_;                          // 4194304

  size_t off = 0;
  auto carve = [&](size_t bytes) -> void* {
    void* p = (char*)d_ws + off;
    off += (bytes + 255) & ~(size_t)255;
    return p;
  };
  unsigned short* Whh0r = (unsigned short*)carve((size_t)NG_ * 1024 * 2);
  unsigned short* Wcatr = (unsigned short*)carve((size_t)NG_ * 2048 * 2);
  unsigned short* h0b[2], *h1b[2];
  h0b[0] = (unsigned short*)carve((size_t)BH * 2);
  h0b[1] = (unsigned short*)carve((size_t)BH * 2);
  h1b[0] = (unsigned short*)carve((size_t)BH * 2);
  h1b[1] = (unsigned short*)carve((size_t)BH * 2);
  float* c0 = (float*)carve((size_t)BH * 4);
  float* c1 = (float*)carve((size_t)BH * 4);
  float* bias0r = (float*)carve(NG_ * 4);
  float* bias1r = (float*)carve(NG_ * 4);
  float* wi0r   = (float*)carve(NG_ * 2 * 4);
  int*   xidx   = (int*)carve(B * 4);

  hipLaunchKernelGGL(prep_w0,   dim3((NG_ * 1024 / 4) / 256), dim3(256), 0, stream, Whh0, Whh0r);
  hipLaunchKernelGGL(prep_wcat, dim3((NG_ * 2048 / 4) / 256), dim3(256), 0, stream, Wih1, Whh1, Wcatr);
  hipLaunchKernelGGL(prep_small, dim3(NG_ / 256), dim3(256), 0, stream,
                     Wih0, bih0, bhh0, bih1, bhh1, bias0r, bias1r, wi0r);
  hipLaunchKernelGGL(prep_state, dim3((BH / 4) / 256), dim3(256), 0, stream,
                     h, c, h0b[0], h1b[0], c0, c1, BH);

  dim3 ggrid(NG_ / 128, B / 64);                  // 32 x 64 = 2048 blocks (~6/CU)
  dim3 gblk(256);
  float* out = (float*)d_out;

  for (int t = 0; t < pred_len; ++t) {
    const int cur = t & 1, nxt = cur ^ 1;
    hipLaunchKernelGGL(lstm_gemm_cell, ggrid, gblk, 0, stream,
                       h0b[cur], (const unsigned short*)nullptr, 1024, Whh0r,
                       bias0r, wi0r, xidx, (t > 0) ? 1 : 0, c0, h0b[nxt]);
    hipLaunchKernelGGL(lstm_gemm_cell, ggrid, gblk, 0, stream,
                       h0b[nxt], h1b[cur], 2048, Wcatr,
                       bias1r, (const float*)nullptr, (const int*)nullptr, 0, c1, h1b[nxt]);
    hipLaunchKernelGGL(fc_argmax, dim3(B / 4), dim3(256), 0, stream,
                       h1b[nxt], fcW, fcb, out, xidx, t, pred_len);
  }
}

// Round 12
// 8585.908 us; speedup vs baseline: 1.3192x; 1.3192x over previous
//
#include <hip/hip_runtime.h>
#include <stdint.h>

#define H_ 1024
#define NG_ 4096   // 4*H

typedef float f32x4 __attribute__((ext_vector_type(4)));
typedef __bf16 bf16x8 __attribute__((ext_vector_type(8)));

__device__ __forceinline__ unsigned short f2bf(float f) {
  union { float f; uint32_t u; } v; v.f = f;
  uint32_t r = v.u + 0x7FFFu + ((v.u >> 16) & 1u);
  return (unsigned short)(r >> 16);
}
__device__ __forceinline__ float bf2f(unsigned short b) {
  union { uint32_t u; float f; } v; v.u = ((uint32_t)b) << 16; return v.f;
}

__device__ __forceinline__ void gload_lds16(const void* g, void* l) {
  __builtin_amdgcn_global_load_lds(
      (const __attribute__((address_space(1))) void*)g,
      (__attribute__((address_space(3))) void*)l, 16, 0, 0);
}

__device__ __forceinline__ float sigm(float x) { return 1.f / (1.f + __expf(-x)); }
__device__ __forceinline__ float tanh_(float x) { return 1.f - 2.f / (__expf(2.f * x) + 1.f); }

// ---------------------------------------------------------------------------
// Weight prep: permute rows r = (j>>4)*64 + gate*16 + (j&15)  (old = gate*H + j)
// so a 64-wide column group holds 16 units x 4 gates, gate index = n-frag index.
// ---------------------------------------------------------------------------
__global__ void prep_w0(const float* __restrict__ Whh0, unsigned short* __restrict__ Wr) {
  int i = (blockIdx.x * 256 + threadIdx.x) * 4;           // over 4096*1024
  int r = i >> 10, k = i & 1023;
  int gate = (r >> 4) & 3;
  int j = ((r >> 6) << 4) + (r & 15);
  const float4 v = *(const float4*)(Whh0 + (size_t)(gate * H_ + j) * H_ + k);
  ushort4 o; o.x = f2bf(v.x); o.y = f2bf(v.y); o.z = f2bf(v.z); o.w = f2bf(v.w);
  *(ushort4*)(Wr + i) = o;
}

__global__ void prep_wcat(const float* __restrict__ Wih1, const float* __restrict__ Whh1,
                          unsigned short* __restrict__ Wr) {
  int i = (blockIdx.x * 256 + threadIdx.x) * 4;           // over 4096*2048
  int r = i >> 11, k = i & 2047;
  int gate = (r >> 4) & 3;
  int j = ((r >> 6) << 4) + (r & 15);
  const float* src = (k < 1024) ? (Wih1 + (size_t)(gate * H_ + j) * H_ + k)
                                : (Whh1 + (size_t)(gate * H_ + j) * H_ + (k - 1024));
  const float4 v = *(const float4*)src;
  ushort4 o; o.x = f2bf(v.x); o.y = f2bf(v.y); o.z = f2bf(v.z); o.w = f2bf(v.w);
  *(ushort4*)(Wr + (size_t)r * 2048 + k) = o;
}

__global__ void prep_small(const float* __restrict__ Wih0,
                           const float* __restrict__ bih0, const float* __restrict__ bhh0,
                           const float* __restrict__ bih1, const float* __restrict__ bhh1,
                           float* __restrict__ bias0r, float* __restrict__ bias1r,
                           float* __restrict__ wi0r) {
  int r = blockIdx.x * 256 + threadIdx.x;                 // over 4096
  int gate = (r >> 4) & 3;
  int j = ((r >> 6) << 4) + (r & 15);
  int old = gate * H_ + j;
  bias0r[r] = bih0[old] + bhh0[old];
  bias1r[r] = bih1[old] + bhh1[old];
  wi0r[r * 2 + 0] = Wih0[old * 2 + 0];
  wi0r[r * 2 + 1] = Wih0[old * 2 + 1];
}

__global__ void prep_state(const float* __restrict__ h, const float* __restrict__ c,
                           unsigned short* __restrict__ h0b, unsigned short* __restrict__ h1b,
                           float* __restrict__ c0, float* __restrict__ c1, int bh) {
  int i = (blockIdx.x * 256 + threadIdx.x) * 4;           // over B*H
  float4 a = *(const float4*)(h + i);
  float4 b = *(const float4*)(h + (size_t)bh + i);
  ushort4 oa; oa.x = f2bf(a.x); oa.y = f2bf(a.y); oa.z = f2bf(a.z); oa.w = f2bf(a.w);
  ushort4 ob; ob.x = f2bf(b.x); ob.y = f2bf(b.y); ob.z = f2bf(b.z); ob.w = f2bf(b.w);
  *(ushort4*)(h0b + i) = oa;
  *(ushort4*)(h1b + i) = ob;
  *(float4*)(c0 + i) = *(const float4*)(c + i);
  *(float4*)(c1 + i) = *(const float4*)(c + (size_t)bh + i);
}

// ---------------------------------------------------------------------------
// Fused GEMM(K=1024) + LSTM cell, R7 structure (128x128 tile, BK=64, 4 waves,
// single-buffered swizzled LDS, 4 blocks/CU). Split-step dataflow:
//  - A-phase (grid 32 x 2*MB): by<MB  -> G0 = h0@Whh0^T + cell (as R7);
//                              by>=MB -> Gpart = h1@Whh1^T, stored bf16-packed
//    in MFMA-fragment order: u32[block*8192 + (m*8+n*2+q2)*256 + tid].
//  - B-phase (grid 32 x MB): G1 = h0n@Wih1^T + Gpart + bias -> cell.
// Weight row stride KsB is passed separately (Wcat halves share storage).
// ---------------------------------------------------------------------------
__global__ void __launch_bounds__(256, 4)
lstm_step(const unsigned short* __restrict__ A,
          const unsigned short* __restrict__ Bw, int KsB,
          const float* __restrict__ biasr,
          const float* __restrict__ wi0r,
          const int* __restrict__ xidx, int have_x,
          float* __restrict__ Cst,
          unsigned short* __restrict__ Hout,
          const unsigned short* __restrict__ Gin,
          int myb,
          const unsigned short* __restrict__ A2,
          const unsigned short* __restrict__ Bw2, int KsB2,
          unsigned short* __restrict__ Gout) {
  __shared__ unsigned short As[128 * 64];
  __shared__ unsigned short Bs[128 * 64];
  const int tid  = threadIdx.x;
  const int lane = tid & 63;
  const int wv   = tid >> 6;
  const int wm   = wv >> 1, wn = wv & 1;

  const int by = blockIdx.y, bx = blockIdx.x;
  const bool gmode = (A2 != nullptr) && (by >= myb);
  const unsigned short* Ap = gmode ? A2 : A;
  const unsigned short* Bp = gmode ? Bw2 : Bw;
  const int Ks  = gmode ? KsB2 : KsB;
  const int tmb = gmode ? (by - myb) : by;
  const int tile_m = tmb * 128;
  const int tile_n = bx * 128;

  f32x4 acc[4][4];
#pragma unroll
  for (int m = 0; m < 4; ++m)
#pragma unroll
    for (int n = 0; n < 4; ++n) acc[m][n] = (f32x4)0.f;

  // staging: chunk = 8 rows x 64 cols; dest linear, source col slot ^= row&7.
  const int lrow = lane >> 3;
  const int lk   = ((lane & 7) ^ lrow) * 8;

  for (int kt = 0; kt < 16; ++kt) {
    const int k0 = kt << 6;
#pragma unroll
    for (int i = 0; i < 4; ++i) {
      int chunk = wv * 4 + i;
      int row = chunk * 8 + lrow;
      gload_lds16(Ap + (size_t)(tile_m + row) * H_ + k0 + lk, (void*)&As[chunk * 512]);
    }
#pragma unroll
    for (int i = 0; i < 4; ++i) {
      int chunk = wv * 4 + i;
      int row = chunk * 8 + lrow;
      gload_lds16(Bp + (size_t)(tile_n + row) * Ks + k0 + lk, (void*)&Bs[chunk * 512]);
    }
    __syncthreads();

    const char* Ab = (const char*)As;
    const char* Bb = (const char*)Bs;
    const int arow = wm * 64 + (lane & 15);
    const int brow = wn * 64 + (lane & 15);
    const int khi  = lane >> 4;
    const int x7   = lane & 7;
    const int ksw0 = ((0 + khi) ^ x7) * 16;
    const int ksw1 = ((4 + khi) ^ x7) * 16;
#pragma unroll
    for (int ks = 0; ks < 2; ++ks) {
      const int ksw = ks ? ksw1 : ksw0;
      bf16x8 af[4], bfr[4];
#pragma unroll
      for (int m = 0; m < 4; ++m)
        af[m] = *(const bf16x8*)(Ab + (arow + m * 16) * 128 + ksw);
#pragma unroll
      for (int n = 0; n < 4; ++n)
        bfr[n] = *(const bf16x8*)(Bb + (brow + n * 16) * 128 + ksw);
#pragma unroll
      for (int m = 0; m < 4; ++m)
#pragma unroll
        for (int n = 0; n < 4; ++n)
          acc[m][n] = __builtin_amdgcn_mfma_f32_16x16x32_bf16(af[m], bfr[n], acc[m][n], 0, 0, 0);
    }
    __syncthreads();
  }

  // ---- gates-only mode: store packed bf16 partials, done ----
  if (gmode) {
    uint32_t* gp = (uint32_t*)Gout + ((size_t)(tmb * gridDim.x + bx) << 13) + tid;
#pragma unroll
    for (int m = 0; m < 4; ++m)
#pragma unroll
      for (int n = 0; n < 4; ++n)
#pragma unroll
        for (int q2 = 0; q2 < 2; ++q2) {
          uint32_t v = (uint32_t)f2bf(acc[m][n][q2 * 2]) |
                       ((uint32_t)f2bf(acc[m][n][q2 * 2 + 1]) << 16);
          gp[(m * 8 + n * 2 + q2) * 256] = v;
        }
    return;
  }

  // ---- add stored partial gates (B-phase) ----
  if (Gin) {
    const uint32_t* gp = (const uint32_t*)Gin + ((size_t)(by * gridDim.x + bx) << 13) + tid;
#pragma unroll
    for (int m = 0; m < 4; ++m)
#pragma unroll
      for (int n = 0; n < 4; ++n)
#pragma unroll
        for (int q2 = 0; q2 < 2; ++q2) {
          uint32_t v = gp[(m * 8 + n * 2 + q2) * 256];
          acc[m][n][q2 * 2]     += bf2f((unsigned short)(v & 0xffff));
          acc[m][n][q2 * 2 + 1] += bf2f((unsigned short)(v >> 16));
        }
  }

  // ---- epilogue: fused LSTM cell ----
  const int cl = lane & 15;
  const int rq = (lane >> 4) * 4;
  const int jgrp = (tile_n >> 6) + wn;
  const int j = jgrp * 16 + cl;
  float bias[4], w0v[4] = {0, 0, 0, 0}, w1v[4] = {0, 0, 0, 0};
#pragma unroll
  for (int n = 0; n < 4; ++n) {
    int colr = tile_n + wn * 64 + n * 16 + cl;
    bias[n] = biasr[colr];
    if (have_x) { w0v[n] = wi0r[colr * 2]; w1v[n] = wi0r[colr * 2 + 1]; }
  }
#pragma unroll
  for (int m = 0; m < 4; ++m) {
#pragma unroll
    for (int q = 0; q < 4; ++q) {
      int row = tile_m + wm * 64 + m * 16 + rq + q;
      float gi = acc[m][0][q] + bias[0];
      float gf = acc[m][1][q] + bias[1];
      float gg = acc[m][2][q] + bias[2];
      float go = acc[m][3][q] + bias[3];
      if (have_x) {
        int x = xidx[row];
        gi += x ? w1v[0] : w0v[0];
        gf += x ? w1v[1] : w0v[1];
        gg += x ? w1v[2] : w0v[2];
        go += x ? w1v[3] : w0v[3];
      }
      size_t off = (size_t)row * H_ + j;
      float cp = Cst[off];
      float cn = sigm(gf) * cp + sigm(gi) * tanh_(gg);
      float hn = sigm(go) * tanh_(cn);
      Cst[off] = cn;
      Hout[off] = f2bf(hn);
    }
  }
}

// ---------------------------------------------------------------------------
// fc head: logits = h1 @ fcW^T + fcb, write out[b,t,:], argmax -> xidx
// ---------------------------------------------------------------------------
__global__ void fc_argmax(const unsigned short* __restrict__ h1,
                          const float* __restrict__ fcW, const float* __restrict__ fcb,
                          float* __restrict__ out, int* __restrict__ xidx,
                          int t, int pred_len) {
  const int lane = threadIdx.x & 63;
  const int wv = threadIdx.x >> 6;
  const int row = blockIdx.x * 4 + wv;
  const unsigned short* hp = h1 + (size_t)row * H_ + lane * 16;
  float d0 = 0.f, d1 = 0.f;
#pragma unroll
  for (int u = 0; u < 2; ++u) {
    ushort4 ha = *(const ushort4*)(hp + u * 8);
    ushort4 hb = *(const ushort4*)(hp + u * 8 + 4);
    float hv[8] = { bf2f(ha.x), bf2f(ha.y), bf2f(ha.z), bf2f(ha.w),
                    bf2f(hb.x), bf2f(hb.y), bf2f(hb.z), bf2f(hb.w) };
#pragma unroll
    for (int e = 0; e < 8; ++e) {
      int k = lane * 16 + u * 8 + e;
      d0 += hv[e] * fcW[k];
      d1 += hv[e] * fcW[H_ + k];
    }
  }
#pragma unroll
  for (int off = 32; off > 0; off >>= 1) {
    d0 += __shfl_xor(d0, off);
    d1 += __shfl_xor(d1, off);
  }
  if (lane == 0) {
    d0 += fcb[0]; d1 += fcb[1];
    size_t o = ((size_t)row * pred_len + t) * 2;
    out[o] = d0; out[o + 1] = d1;
    xidx[row] = (d1 > d0) ? 1 : 0;
  }
}

// ---------------------------------------------------------------------------
extern "C" void kernel_launch(void* const* d_in, const int* in_sizes, int n_in,
                              void* d_out, int out_size, void* d_ws, size_t ws_size,
                              hipStream_t stream) {
  const float* h     = (const float*)d_in[0];
  const float* c     = (const float*)d_in[1];
  const float* Wih0  = (const float*)d_in[2];
  const float* Whh0  = (const float*)d_in[3];
  const float* bih0  = (const float*)d_in[4];
  const float* bhh0  = (const float*)d_in[5];
  const float* Wih1  = (const float*)d_in[6];
  const float* Whh1  = (const float*)d_in[7];
  const float* bih1  = (const float*)d_in[8];
  const float* bhh1  = (const float*)d_in[9];
  const float* fcW   = (const float*)d_in[10];
  const float* fcb   = (const float*)d_in[11];

  const int B = in_sizes[0] / (2 * H_);           // 4096
  const int pred_len = out_size / (B * 2);        // 64
  const int BH = B * H_;                          // 4194304
  const int MB = B / 128;                         // 32 m-blocks

  size_t off = 0;
  auto carve = [&](size_t bytes) -> void* {
    void* p = (char*)d_ws + off;
    off += (bytes + 255) & ~(size_t)255;
    return p;
  };
  unsigned short* Whh0r = (unsigned short*)carve((size_t)NG_ * 1024 * 2);
  unsigned short* Wcatr = (unsigned short*)carve((size_t)NG_ * 2048 * 2);
  unsigned short* h0b[2], *h1b[2];
  h0b[0] = (unsigned short*)carve((size_t)BH * 2);
  h0b[1] = (unsigned short*)carve((size_t)BH * 2);
  h1b[0] = (unsigned short*)carve((size_t)BH * 2);
  h1b[1] = (unsigned short*)carve((size_t)BH * 2);
  float* c0 = (float*)carve((size_t)BH * 4);
  float* c1 = (float*)carve((size_t)BH * 4);
  float* bias0r = (float*)carve(NG_ * 4);
  float* bias1r = (float*)carve(NG_ * 4);
  float* wi0r   = (float*)carve(NG_ * 2 * 4);
  int*   xidx   = (int*)carve(B * 4);
  unsigned short* G1p = (unsigned short*)carve((size_t)B * NG_ * 2);   // 32 MB

  hipLaunchKernelGGL(prep_w0,   dim3((NG_ * 1024 / 4) / 256), dim3(256), 0, stream, Whh0, Whh0r);
  hipLaunchKernelGGL(prep_wcat, dim3((NG_ * 2048 / 4) / 256), dim3(256), 0, stream, Wih1, Whh1, Wcatr);
  hipLaunchKernelGGL(prep_small, dim3(NG_ / 256), dim3(256), 0, stream,
                     Wih0, bih0, bhh0, bih1, bhh1, bias0r, bias1r, wi0r);
  hipLaunchKernelGGL(prep_state, dim3((BH / 4) / 256), dim3(256), 0, stream,
                     h, c, h0b[0], h1b[0], c0, c1, BH);

  dim3 ggridA(NG_ / 128, MB * 2);                 // 32 x 64: G0+cell | h1@Whh1^T
  dim3 ggridB(NG_ / 128, MB);                     // 32 x 32: G1 + partial + cell
  dim3 gblk(256);
  float* out = (float*)d_out;

  for (int t = 0; t < pred_len; ++t) {
    const int cur = t & 1, nxt = cur ^ 1;
    // A-phase: layer-0 full cell  +  layer-1 h1-half gates (independent work)
    hipLaunchKernelGGL(lstm_step, ggridA, gblk, 0, stream,
                       h0b[cur], Whh0r, 1024,
                       bias0r, wi0r, xidx, (t > 0) ? 1 : 0,
                       c0, h0b[nxt],
                       (const unsigned short*)nullptr,
                       MB, h1b[cur], Wcatr + 1024, 2048, G1p);
    // B-phase: layer-1 h0n-half + stored partial + cell
    hipLaunchKernelGGL(lstm_step, ggridB, gblk, 0, stream,
                       h0b[nxt], Wcatr, 2048,
                       bias1r, (const float*)nullptr, (const int*)nullptr, 0,
                       c1, h1b[nxt],
                       G1p,
                       MB, (const unsigned short*)nullptr,
                       (const unsigned short*)nullptr, 0, (unsigned short*)nullptr);
    // fc head + argmax feedback
    hipLaunchKernelGGL(fc_argmax, dim3(B / 4), dim3(256), 0, stream,
                       h1b[nxt], fcW, fcb, out, xidx, t, pred_len);
  }
}

// Round 13
// 8495.113 us; speedup vs baseline: 1.3333x; 1.0107x over previous
//
#include <hip/hip_runtime.h>
#include <stdint.h>

#define H_ 1024
#define NG_ 4096   // 4*H

typedef float f32x4 __attribute__((ext_vector_type(4)));
typedef __bf16 bf16x8 __attribute__((ext_vector_type(8)));

__device__ __forceinline__ unsigned short f2bf(float f) {
  union { float f; uint32_t u; } v; v.f = f;
  uint32_t r = v.u + 0x7FFFu + ((v.u >> 16) & 1u);
  return (unsigned short)(r >> 16);
}
__device__ __forceinline__ float bf2f(unsigned short b) {
  union { uint32_t u; float f; } v; v.u = ((uint32_t)b) << 16; return v.f;
}

__device__ __forceinline__ void gload_lds16(const void* g, void* l) {
  __builtin_amdgcn_global_load_lds(
      (const __attribute__((address_space(1))) void*)g,
      (__attribute__((address_space(3))) void*)l, 16, 0, 0);
}

__device__ __forceinline__ float sigm(float x) { return 1.f / (1.f + __expf(-x)); }
__device__ __forceinline__ float tanh_(float x) { return 1.f - 2.f / (__expf(2.f * x) + 1.f); }

// ---------------------------------------------------------------------------
// Weight prep: permute rows r = (j>>4)*64 + gate*16 + (j&15)  (old = gate*H + j)
// so a 64-wide column group holds 16 units x 4 gates, gate index = n-frag index.
// ---------------------------------------------------------------------------
__global__ void prep_w0(const float* __restrict__ Whh0, unsigned short* __restrict__ Wr) {
  int i = (blockIdx.x * 256 + threadIdx.x) * 4;           // over 4096*1024
  int r = i >> 10, k = i & 1023;
  int gate = (r >> 4) & 3;
  int j = ((r >> 6) << 4) + (r & 15);
  const float4 v = *(const float4*)(Whh0 + (size_t)(gate * H_ + j) * H_ + k);
  ushort4 o; o.x = f2bf(v.x); o.y = f2bf(v.y); o.z = f2bf(v.z); o.w = f2bf(v.w);
  *(ushort4*)(Wr + i) = o;
}

__global__ void prep_wcat(const float* __restrict__ Wih1, const float* __restrict__ Whh1,
                          unsigned short* __restrict__ Wr) {
  int i = (blockIdx.x * 256 + threadIdx.x) * 4;           // over 4096*2048
  int r = i >> 11, k = i & 2047;
  int gate = (r >> 4) & 3;
  int j = ((r >> 6) << 4) + (r & 15);
  const float* src = (k < 1024) ? (Wih1 + (size_t)(gate * H_ + j) * H_ + k)
                                : (Whh1 + (size_t)(gate * H_ + j) * H_ + (k - 1024));
  const float4 v = *(const float4*)src;
  ushort4 o; o.x = f2bf(v.x); o.y = f2bf(v.y); o.z = f2bf(v.z); o.w = f2bf(v.w);
  *(ushort4*)(Wr + (size_t)r * 2048 + k) = o;
}

__global__ void prep_small(const float* __restrict__ Wih0,
                           const float* __restrict__ bih0, const float* __restrict__ bhh0,
                           const float* __restrict__ bih1, const float* __restrict__ bhh1,
                           float* __restrict__ bias0r, float* __restrict__ bias1r,
                           float* __restrict__ wi0r) {
  int r = blockIdx.x * 256 + threadIdx.x;                 // over 4096
  int gate = (r >> 4) & 3;
  int j = ((r >> 6) << 4) + (r & 15);
  int old = gate * H_ + j;
  bias0r[r] = bih0[old] + bhh0[old];
  bias1r[r] = bih1[old] + bhh1[old];
  wi0r[r * 2 + 0] = Wih0[old * 2 + 0];
  wi0r[r * 2 + 1] = Wih0[old * 2 + 1];
}

__global__ void prep_state(const float* __restrict__ h, const float* __restrict__ c,
                           unsigned short* __restrict__ h0b, unsigned short* __restrict__ h1b,
                           float* __restrict__ c0, float* __restrict__ c1, int bh) {
  int i = (blockIdx.x * 256 + threadIdx.x) * 4;           // over B*H
  float4 a = *(const float4*)(h + i);
  float4 b = *(const float4*)(h + (size_t)bh + i);
  ushort4 oa; oa.x = f2bf(a.x); oa.y = f2bf(a.y); oa.z = f2bf(a.z); oa.w = f2bf(a.w);
  ushort4 ob; ob.x = f2bf(b.x); ob.y = f2bf(b.y); ob.z = f2bf(b.z); ob.w = f2bf(b.w);
  *(ushort4*)(h0b + i) = oa;
  *(ushort4*)(h1b + i) = ob;
  *(float4*)(c0 + i) = *(const float4*)(c + i);
  *(float4*)(c1 + i) = *(const float4*)(c + (size_t)bh + i);
}

// ---------------------------------------------------------------------------
// Fused GEMM + LSTM cell.  R13: 128x128 block tile, BK=64, **2 waves** (2M x
// 1N), wave-tile 64x128 (acc 4x8).  LDS read per block-Ktile drops 64->48 KB
// (A read once, B twice) -> LDS pipe no longer dominant (43.7 FLOP/LDS-byte).
// Same both-sides XOR swizzle as R7; 4 blocks/CU (LDS 128 KB), grid 1024.
// ---------------------------------------------------------------------------
__global__ void __launch_bounds__(128, 2)
lstm_gemm_cell(const unsigned short* __restrict__ A0,
               const unsigned short* __restrict__ A1,
               int Ktot,
               const unsigned short* __restrict__ Bw,
               const float* __restrict__ biasr,
               const float* __restrict__ wi0r,
               const int* __restrict__ xidx,
               int have_x,
               float* __restrict__ Cst,
               unsigned short* __restrict__ Hout) {
  __shared__ unsigned short As[128 * 64];
  __shared__ unsigned short Bs[128 * 64];
  const int tid  = threadIdx.x;
  const int lane = tid & 63;
  const int wv   = tid >> 6;                       // 0..1 = M half
  const int tile_m = blockIdx.y * 128;
  const int tile_n = blockIdx.x * 128;

  f32x4 acc[4][8];
#pragma unroll
  for (int m = 0; m < 4; ++m)
#pragma unroll
    for (int n = 0; n < 8; ++n) acc[m][n] = (f32x4)0.f;

  // staging: chunk = 8 rows x 64 cols (1 KB, one wave-gload).
  // dest linear (base + lane*16); source col slot pre-XORed by row&7.
  const int lrow = lane >> 3;                      // row within chunk (= row&7)
  const int lk   = ((lane & 7) ^ lrow) * 8;        // inv-swizzled global col

  const int nk = Ktot >> 6;
  for (int kt = 0; kt < nk; ++kt) {
    const int k0 = kt << 6;
    const unsigned short* Ap; int kl;
    if (k0 < 1024) { Ap = A0; kl = k0; } else { Ap = A1; kl = k0 - 1024; }
#pragma unroll
    for (int i = 0; i < 8; ++i) {
      int chunk = wv * 8 + i;
      int row = chunk * 8 + lrow;
      gload_lds16(Ap + (size_t)(tile_m + row) * H_ + kl + lk, (void*)&As[chunk * 512]);
    }
#pragma unroll
    for (int i = 0; i < 8; ++i) {
      int chunk = wv * 8 + i;
      int row = chunk * 8 + lrow;
      gload_lds16(Bw + (size_t)(tile_n + row) * Ktot + k0 + lk, (void*)&Bs[chunk * 512]);
    }
    __syncthreads();

    const char* Ab = (const char*)As;
    const char* Bb = (const char*)Bs;
    const int cl   = lane & 15;
    const int khi  = lane >> 4;                    // 0..3
    const int x7   = lane & 7;                     // row&7 of rows this lane reads
    const int ksw0 = ((0 + khi) ^ x7) * 16;        // physical byte off, ks=0
    const int ksw1 = ((4 + khi) ^ x7) * 16;        // ks=1
#pragma unroll
    for (int ks = 0; ks < 2; ++ks) {
      const int ksw = ks ? ksw1 : ksw0;
      bf16x8 af[4], bfr[8];
#pragma unroll
      for (int m = 0; m < 4; ++m)
        af[m] = *(const bf16x8*)(Ab + (wv * 64 + m * 16 + cl) * 128 + ksw);
#pragma unroll
      for (int n = 0; n < 8; ++n)
        bfr[n] = *(const bf16x8*)(Bb + (n * 16 + cl) * 128 + ksw);
#pragma unroll
      for (int m = 0; m < 4; ++m)
#pragma unroll
        for (int n = 0; n < 8; ++n)
          acc[m][n] = __builtin_amdgcn_mfma_f32_16x16x32_bf16(af[m], bfr[n], acc[m][n], 0, 0, 0);
    }
    __syncthreads();
  }

  // ---- epilogue: fused LSTM cell ----
  // acc[m][n]: row = tile_m + wv*64 + m*16 + khi*4 + q; col = tile_n + n*16 + cl
  // gate g = n&3, half = n>>2; unit j = ((tile_n>>6)+half)*16 + cl.
  const int cl = lane & 15;
  const int rq = (lane >> 4) * 4;
  float bias[2][4], w0v[2][4] = {{0}}, w1v[2][4] = {{0}};
#pragma unroll
  for (int half = 0; half < 2; ++half)
#pragma unroll
    for (int g = 0; g < 4; ++g) {
      int colr = tile_n + half * 64 + g * 16 + cl;
      bias[half][g] = biasr[colr];
      if (have_x) { w0v[half][g] = wi0r[colr * 2]; w1v[half][g] = wi0r[colr * 2 + 1]; }
    }
#pragma unroll
  for (int m = 0; m < 4; ++m) {
#pragma unroll
    for (int q = 0; q < 4; ++q) {
      int row = tile_m + wv * 64 + m * 16 + rq + q;
      int x = 0;
      if (have_x) x = xidx[row];
#pragma unroll
      for (int half = 0; half < 2; ++half) {
        float gi = acc[m][half * 4 + 0][q] + bias[half][0];
        float gf = acc[m][half * 4 + 1][q] + bias[half][1];
        float gg = acc[m][half * 4 + 2][q] + bias[half][2];
        float go = acc[m][half * 4 + 3][q] + bias[half][3];
        if (have_x) {
          gi += x ? w1v[half][0] : w0v[half][0];
          gf += x ? w1v[half][1] : w0v[half][1];
          gg += x ? w1v[half][2] : w0v[half][2];
          go += x ? w1v[half][3] : w0v[half][3];
        }
        int j = ((tile_n >> 6) + half) * 16 + cl;
        size_t off = (size_t)row * H_ + j;
        float cp = Cst[off];
        float cn = sigm(gf) * cp + sigm(gi) * tanh_(gg);
        float hn = sigm(go) * tanh_(cn);
        Cst[off] = cn;
        Hout[off] = f2bf(hn);
      }
    }
  }
}

// ---------------------------------------------------------------------------
// fc head: logits = h1 @ fcW^T + fcb, write out[b,t,:], argmax -> xidx
// ---------------------------------------------------------------------------
__global__ void fc_argmax(const unsigned short* __restrict__ h1,
                          const float* __restrict__ fcW, const float* __restrict__ fcb,
                          float* __restrict__ out, int* __restrict__ xidx,
                          int t, int pred_len) {
  const int lane = threadIdx.x & 63;
  const int wv = threadIdx.x >> 6;
  const int row = blockIdx.x * 4 + wv;
  const unsigned short* hp = h1 + (size_t)row * H_ + lane * 16;
  float d0 = 0.f, d1 = 0.f;
#pragma unroll
  for (int u = 0; u < 2; ++u) {
    ushort4 ha = *(const ushort4*)(hp + u * 8);
    ushort4 hb = *(const ushort4*)(hp + u * 8 + 4);
    float hv[8] = { bf2f(ha.x), bf2f(ha.y), bf2f(ha.z), bf2f(ha.w),
                    bf2f(hb.x), bf2f(hb.y), bf2f(hb.z), bf2f(hb.w) };
#pragma unroll
    for (int e = 0; e < 8; ++e) {
      int k = lane * 16 + u * 8 + e;
      d0 += hv[e] * fcW[k];
      d1 += hv[e] * fcW[H_ + k];
    }
  }
#pragma unroll
  for (int off = 32; off > 0; off >>= 1) {
    d0 += __shfl_xor(d0, off);
    d1 += __shfl_xor(d1, off);
  }
  if (lane == 0) {
    d0 += fcb[0]; d1 += fcb[1];
    size_t o = ((size_t)row * pred_len + t) * 2;
    out[o] = d0; out[o + 1] = d1;
    xidx[row] = (d1 > d0) ? 1 : 0;
  }
}

// ---------------------------------------------------------------------------
extern "C" void kernel_launch(void* const* d_in, const int* in_sizes, int n_in,
                              void* d_out, int out_size, void* d_ws, size_t ws_size,
                              hipStream_t stream) {
  const float* h     = (const float*)d_in[0];
  const float* c     = (const float*)d_in[1];
  const float* Wih0  = (const float*)d_in[2];
  const float* Whh0  = (const float*)d_in[3];
  const float* bih0  = (const float*)d_in[4];
  const float* bhh0  = (const float*)d_in[5];
  const float* Wih1  = (const float*)d_in[6];
  const float* Whh1  = (const float*)d_in[7];
  const float* bih1  = (const float*)d_in[8];
  const float* bhh1  = (const float*)d_in[9];
  const float* fcW   = (const float*)d_in[10];
  const float* fcb   = (const float*)d_in[11];

  const int B = in_sizes[0] / (2 * H_);           // 4096
  const int pred_len = out_size / (B * 2);        // 64
  const int BH = B * H_;                          // 4194304

  size_t off = 0;
  auto carve = [&](size_t bytes) -> void* {
    void* p = (char*)d_ws + off;
    off += (bytes + 255) & ~(size_t)255;
    return p;
  };
  unsigned short* Whh0r = (unsigned short*)carve((size_t)NG_ * 1024 * 2);
  unsigned short* Wcatr = (unsigned short*)carve((size_t)NG_ * 2048 * 2);
  unsigned short* h0b[2], *h1b[2];
  h0b[0] = (unsigned short*)carve((size_t)BH * 2);
  h0b[1] = (unsigned short*)carve((size_t)BH * 2);
  h1b[0] = (unsigned short*)carve((size_t)BH * 2);
  h1b[1] = (unsigned short*)carve((size_t)BH * 2);
  float* c0 = (float*)carve((size_t)BH * 4);
  float* c1 = (float*)carve((size_t)BH * 4);
  float* bias0r = (float*)carve(NG_ * 4);
  float* bias1r = (float*)carve(NG_ * 4);
  float* wi0r   = (float*)carve(NG_ * 2 * 4);
  int*   xidx   = (int*)carve(B * 4);

  hipLaunchKernelGGL(prep_w0,   dim3((NG_ * 1024 / 4) / 256), dim3(256), 0, stream, Whh0, Whh0r);
  hipLaunchKernelGGL(prep_wcat, dim3((NG_ * 2048 / 4) / 256), dim3(256), 0, stream, Wih1, Whh1, Wcatr);
  hipLaunchKernelGGL(prep_small, dim3(NG_ / 256), dim3(256), 0, stream,
                     Wih0, bih0, bhh0, bih1, bhh1, bias0r, bias1r, wi0r);
  hipLaunchKernelGGL(prep_state, dim3((BH / 4) / 256), dim3(256), 0, stream,
                     h, c, h0b[0], h1b[0], c0, c1, BH);

  dim3 ggrid(NG_ / 128, B / 128);                 // 32 x 32 = 1024 blocks
  dim3 gblk(128);                                 // 2 waves/block
  float* out = (float*)d_out;

  for (int t = 0; t < pred_len; ++t) {
    const int cur = t & 1, nxt = cur ^ 1;
    hipLaunchKernelGGL(lstm_gemm_cell, ggrid, gblk, 0, stream,
                       h0b[cur], (const unsigned short*)nullptr, 1024, Whh0r,
                       bias0r, wi0r, xidx, (t > 0) ? 1 : 0, c0, h0b[nxt]);
    hipLaunchKernelGGL(lstm_gemm_cell, ggrid, gblk, 0, stream,
                       h0b[nxt], h1b[cur], 2048, Wcatr,
                       bias1r, (const float*)nullptr, (const int*)nullptr, 0, c1, h1b[nxt]);
    hipLaunchKernelGGL(fc_argmax, dim3(B / 4), dim3(256), 0, stream,
                       h1b[nxt], fcW, fcb, out, xidx, t, pred_len);
  }
}

// Round 14
// 7337.666 us; speedup vs baseline: 1.5436x; 1.1577x over previous
//
#include <hip/hip_runtime.h>
#include <stdint.h>

#define H_ 1024
#define NG_ 4096   // 4*H

typedef float f32x4 __attribute__((ext_vector_type(4)));
typedef __bf16 bf16x8 __attribute__((ext_vector_type(8)));

__device__ __forceinline__ unsigned short f2bf(float f) {
  union { float f; uint32_t u; } v; v.f = f;
  uint32_t r = v.u + 0x7FFFu + ((v.u >> 16) & 1u);
  return (unsigned short)(r >> 16);
}
__device__ __forceinline__ float bf2f(unsigned short b) {
  union { uint32_t u; float f; } v; v.u = ((uint32_t)b) << 16; return v.f;
}

__device__ __forceinline__ void gload_lds16(const void* g, void* l) {
  __builtin_amdgcn_global_load_lds(
      (const __attribute__((address_space(1))) void*)g,
      (__attribute__((address_space(3))) void*)l, 16, 0, 0);
}

__device__ __forceinline__ float sigm(float x) { return 1.f / (1.f + __expf(-x)); }
__device__ __forceinline__ float tanh_(float x) { return 1.f - 2.f / (__expf(2.f * x) + 1.f); }

// ---------------------------------------------------------------------------
// Weight prep: permute rows r = (j>>4)*64 + gate*16 + (j&15)  (old = gate*H + j)
// so a 64-wide column group holds 16 units x 4 gates, gate index = n-frag index.
// ---------------------------------------------------------------------------
__global__ void prep_w0(const float* __restrict__ Whh0, unsigned short* __restrict__ Wr) {
  int i = (blockIdx.x * 256 + threadIdx.x) * 4;           // over 4096*1024
  int r = i >> 10, k = i & 1023;
  int gate = (r >> 4) & 3;
  int j = ((r >> 6) << 4) + (r & 15);
  const float4 v = *(const float4*)(Whh0 + (size_t)(gate * H_ + j) * H_ + k);
  ushort4 o; o.x = f2bf(v.x); o.y = f2bf(v.y); o.z = f2bf(v.z); o.w = f2bf(v.w);
  *(ushort4*)(Wr + i) = o;
}

__global__ void prep_wcat(const float* __restrict__ Wih1, const float* __restrict__ Whh1,
                          unsigned short* __restrict__ Wr) {
  int i = (blockIdx.x * 256 + threadIdx.x) * 4;           // over 4096*2048
  int r = i >> 11, k = i & 2047;
  int gate = (r >> 4) & 3;
  int j = ((r >> 6) << 4) + (r & 15);
  const float* src = (k < 1024) ? (Wih1 + (size_t)(gate * H_ + j) * H_ + k)
                                : (Whh1 + (size_t)(gate * H_ + j) * H_ + (k - 1024));
  const float4 v = *(const float4*)src;
  ushort4 o; o.x = f2bf(v.x); o.y = f2bf(v.y); o.z = f2bf(v.z); o.w = f2bf(v.w);
  *(ushort4*)(Wr + (size_t)r * 2048 + k) = o;
}

__global__ void prep_small(const float* __restrict__ Wih0,
                           const float* __restrict__ bih0, const float* __restrict__ bhh0,
                           const float* __restrict__ bih1, const float* __restrict__ bhh1,
                           float* __restrict__ bias0r, float* __restrict__ bias1r,
                           float* __restrict__ wi0r) {
  int r = blockIdx.x * 256 + threadIdx.x;                 // over 4096
  int gate = (r >> 4) & 3;
  int j = ((r >> 6) << 4) + (r & 15);
  int old = gate * H_ + j;
  bias0r[r] = bih0[old] + bhh0[old];
  bias1r[r] = bih1[old] + bhh1[old];
  wi0r[r * 2 + 0] = Wih0[old * 2 + 0];
  wi0r[r * 2 + 1] = Wih0[old * 2 + 1];
}

__global__ void prep_state(const float* __restrict__ h, const float* __restrict__ c,
                           unsigned short* __restrict__ h0b, unsigned short* __restrict__ h1b,
                           float* __restrict__ c0, float* __restrict__ c1, int bh) {
  int i = (blockIdx.x * 256 + threadIdx.x) * 4;           // over B*H
  float4 a = *(const float4*)(h + i);
  float4 b = *(const float4*)(h + (size_t)bh + i);
  ushort4 oa; oa.x = f2bf(a.x); oa.y = f2bf(a.y); oa.z = f2bf(a.z); oa.w = f2bf(a.w);
  ushort4 ob; ob.x = f2bf(b.x); ob.y = f2bf(b.y); ob.z = f2bf(b.z); ob.w = f2bf(b.w);
  *(ushort4*)(h0b + i) = oa;
  *(ushort4*)(h1b + i) = ob;
  *(float4*)(c0 + i) = *(const float4*)(c + i);
  *(float4*)(c1 + i) = *(const float4*)(c + (size_t)bh + i);
}

// ---------------------------------------------------------------------------
// Fused GEMM + LSTM cell.  Best measured config (R7): 128x128 tile, BK=64,
// 4 waves, single-buffered LDS, 4 blocks/CU occupancy-pipelined, both-sides
// XOR swizzle (slot ^= row&7, 16B slots) -> 0 bank conflicts.
//   - stage: linear LDS dest (gload_lds lane-order), global src col pre-XORed
//   - read : ds_read at slot (ks*4+khi) ^ (lane&7)
// ---------------------------------------------------------------------------
__global__ void lstm_gemm_cell(const unsigned short* __restrict__ A0,
                               const unsigned short* __restrict__ A1,
                               int Ktot,
                               const unsigned short* __restrict__ Bw,
                               const float* __restrict__ biasr,
                               const float* __restrict__ wi0r,
                               const int* __restrict__ xidx,
                               int have_x,
                               float* __restrict__ Cst,
                               unsigned short* __restrict__ Hout) {
  __shared__ unsigned short As[128 * 64];
  __shared__ unsigned short Bs[128 * 64];
  const int tid  = threadIdx.x;
  const int lane = tid & 63;
  const int wv   = tid >> 6;
  const int wm   = wv >> 1, wn = wv & 1;
  const int tile_m = blockIdx.y * 128;
  const int tile_n = blockIdx.x * 128;

  f32x4 acc[4][4];
#pragma unroll
  for (int m = 0; m < 4; ++m)
#pragma unroll
    for (int n = 0; n < 4; ++n) acc[m][n] = (f32x4)0.f;

  // staging: chunk = 8 rows x 64 cols; lane covers row lane>>3, slot lane&7.
  // dest is linear (base + lane*16); source col slot pre-XORed by row&7.
  const int lrow = lane >> 3;                      // row within chunk (= row&7)
  const int lk   = ((lane & 7) ^ lrow) * 8;        // inv-swizzled global col (elems)

  const int nk = Ktot >> 6;
  for (int kt = 0; kt < nk; ++kt) {
    const int k0 = kt << 6;
    const unsigned short* Ap; int kl;
    if (k0 < 1024) { Ap = A0; kl = k0; } else { Ap = A1; kl = k0 - 1024; }
#pragma unroll
    for (int i = 0; i < 4; ++i) {
      int chunk = wv * 4 + i;
      int row = chunk * 8 + lrow;
      gload_lds16(Ap + (size_t)(tile_m + row) * H_ + kl + lk, (void*)&As[chunk * 512]);
    }
#pragma unroll
    for (int i = 0; i < 4; ++i) {
      int chunk = wv * 4 + i;
      int row = chunk * 8 + lrow;
      gload_lds16(Bw + (size_t)(tile_n + row) * Ktot + k0 + lk, (void*)&Bs[chunk * 512]);
    }
    __syncthreads();

    const char* Ab = (const char*)As;
    const char* Bb = (const char*)Bs;
    const int arow = wm * 64 + (lane & 15);
    const int brow = wn * 64 + (lane & 15);
    const int khi  = lane >> 4;                    // 0..3
    const int x7   = lane & 7;                     // row&7 of the rows this lane reads
    const int ksw0 = ((0 + khi) ^ x7) * 16;        // physical byte off, ks=0
    const int ksw1 = ((4 + khi) ^ x7) * 16;        // ks=1
#pragma unroll
    for (int ks = 0; ks < 2; ++ks) {
      const int ksw = ks ? ksw1 : ksw0;
      bf16x8 af[4], bfr[4];
#pragma unroll
      for (int m = 0; m < 4; ++m)
        af[m] = *(const bf16x8*)(Ab + (arow + m * 16) * 128 + ksw);
#pragma unroll
      for (int n = 0; n < 4; ++n)
        bfr[n] = *(const bf16x8*)(Bb + (brow + n * 16) * 128 + ksw);
#pragma unroll
      for (int m = 0; m < 4; ++m)
#pragma unroll
        for (int n = 0; n < 4; ++n)
          acc[m][n] = __builtin_amdgcn_mfma_f32_16x16x32_bf16(af[m], bfr[n], acc[m][n], 0, 0, 0);
    }
    __syncthreads();
  }

  // ---- epilogue: fused LSTM cell ----
  const int cl = lane & 15;
  const int rq = (lane >> 4) * 4;
  const int jgrp = (tile_n >> 6) + wn;             // (tile_n + wn*64)/64
  const int j = jgrp * 16 + cl;
  float bias[4], w0v[4] = {0, 0, 0, 0}, w1v[4] = {0, 0, 0, 0};
#pragma unroll
  for (int n = 0; n < 4; ++n) {
    int colr = tile_n + wn * 64 + n * 16 + cl;
    bias[n] = biasr[colr];
    if (have_x) { w0v[n] = wi0r[colr * 2]; w1v[n] = wi0r[colr * 2 + 1]; }
  }
#pragma unroll
  for (int m = 0; m < 4; ++m) {
#pragma unroll
    for (int q = 0; q < 4; ++q) {
      int row = tile_m + wm * 64 + m * 16 + rq + q;
      float gi = acc[m][0][q] + bias[0];
      float gf = acc[m][1][q] + bias[1];
      float gg = acc[m][2][q] + bias[2];
      float go = acc[m][3][q] + bias[3];
      if (have_x) {
        int x = xidx[row];
        gi += x ? w1v[0] : w0v[0];
        gf += x ? w1v[1] : w0v[1];
        gg += x ? w1v[2] : w0v[2];
        go += x ? w1v[3] : w0v[3];
      }
      size_t off = (size_t)row * H_ + j;
      float cp = Cst[off];
      float cn = sigm(gf) * cp + sigm(gi) * tanh_(gg);
      float hn = sigm(go) * tanh_(cn);
      Cst[off] = cn;
      Hout[off] = f2bf(hn);
    }
  }
}

// ---------------------------------------------------------------------------
// fc head: logits = h1 @ fcW^T + fcb, write out[b,t,:], argmax -> xidx
// ---------------------------------------------------------------------------
__global__ void fc_argmax(const unsigned short* __restrict__ h1,
                          const float* __restrict__ fcW, const float* __restrict__ fcb,
                          float* __restrict__ out, int* __restrict__ xidx,
                          int t, int pred_len) {
  const int lane = threadIdx.x & 63;
  const int wv = threadIdx.x >> 6;
  const int row = blockIdx.x * 4 + wv;
  const unsigned short* hp = h1 + (size_t)row * H_ + lane * 16;
  float d0 = 0.f, d1 = 0.f;
#pragma unroll
  for (int u = 0; u < 2; ++u) {
    ushort4 ha = *(const ushort4*)(hp + u * 8);
    ushort4 hb = *(const ushort4*)(hp + u * 8 + 4);
    float hv[8] = { bf2f(ha.x), bf2f(ha.y), bf2f(ha.z), bf2f(ha.w),
                    bf2f(hb.x), bf2f(hb.y), bf2f(hb.z), bf2f(hb.w) };
#pragma unroll
    for (int e = 0; e < 8; ++e) {
      int k = lane * 16 + u * 8 + e;
      d0 += hv[e] * fcW[k];
      d1 += hv[e] * fcW[H_ + k];
    }
  }
#pragma unroll
  for (int off = 32; off > 0; off >>= 1) {
    d0 += __shfl_xor(d0, off);
    d1 += __shfl_xor(d1, off);
  }
  if (lane == 0) {
    d0 += fcb[0]; d1 += fcb[1];
    size_t o = ((size_t)row * pred_len + t) * 2;
    out[o] = d0; out[o + 1] = d1;
    xidx[row] = (d1 > d0) ? 1 : 0;
  }
}

// ---------------------------------------------------------------------------
extern "C" void kernel_launch(void* const* d_in, const int* in_sizes, int n_in,
                              void* d_out, int out_size, void* d_ws, size_t ws_size,
                              hipStream_t stream) {
  const float* h     = (const float*)d_in[0];
  const float* c     = (const float*)d_in[1];
  const float* Wih0  = (const float*)d_in[2];
  const float* Whh0  = (const float*)d_in[3];
  const float* bih0  = (const float*)d_in[4];
  const float* bhh0  = (const float*)d_in[5];
  const float* Wih1  = (const float*)d_in[6];
  const float* Whh1  = (const float*)d_in[7];
  const float* bih1  = (const float*)d_in[8];
  const float* bhh1  = (const float*)d_in[9];
  const float* fcW   = (const float*)d_in[10];
  const float* fcb   = (const float*)d_in[11];

  const int B = in_sizes[0] / (2 * H_);           // 4096
  const int pred_len = out_size / (B * 2);        // 64
  const int BH = B * H_;                          // 4194304

  size_t off = 0;
  auto carve = [&](size_t bytes) -> void* {
    void* p = (char*)d_ws + off;
    off += (bytes + 255) & ~(size_t)255;
    return p;
  };
  unsigned short* Whh0r = (unsigned short*)carve((size_t)NG_ * 1024 * 2);
  unsigned short* Wcatr = (unsigned short*)carve((size_t)NG_ * 2048 * 2);
  unsigned short* h0b[2], *h1b[2];
  h0b[0] = (unsigned short*)carve((size_t)BH * 2);
  h0b[1] = (unsigned short*)carve((size_t)BH * 2);
  h1b[0] = (unsigned short*)carve((size_t)BH * 2);
  h1b[1] = (unsigned short*)carve((size_t)BH * 2);
  float* c0 = (float*)carve((size_t)BH * 4);
  float* c1 = (float*)carve((size_t)BH * 4);
  float* bias0r = (float*)carve(NG_ * 4);
  float* bias1r = (float*)carve(NG_ * 4);
  float* wi0r   = (float*)carve(NG_ * 2 * 4);
  int*   xidx   = (int*)carve(B * 4);

  hipLaunchKernelGGL(prep_w0,   dim3((NG_ * 1024 / 4) / 256), dim3(256), 0, stream, Whh0, Whh0r);
  hipLaunchKernelGGL(prep_wcat, dim3((NG_ * 2048 / 4) / 256), dim3(256), 0, stream, Wih1, Whh1, Wcatr);
  hipLaunchKernelGGL(prep_small, dim3(NG_ / 256), dim3(256), 0, stream,
                     Wih0, bih0, bhh0, bih1, bhh1, bias0r, bias1r, wi0r);
  hipLaunchKernelGGL(prep_state, dim3((BH / 4) / 256), dim3(256), 0, stream,
                     h, c, h0b[0], h1b[0], c0, c1, BH);

  dim3 ggrid(NG_ / 128, B / 128);                 // 32 x 32 = 1024 blocks (4/CU)
  dim3 gblk(256);
  float* out = (float*)d_out;

  for (int t = 0; t < pred_len; ++t) {
    const int cur = t & 1, nxt = cur ^ 1;
    hipLaunchKernelGGL(lstm_gemm_cell, ggrid, gblk, 0, stream,
                       h0b[cur], (const unsigned short*)nullptr, 1024, Whh0r,
                       bias0r, wi0r, xidx, (t > 0) ? 1 : 0, c0, h0b[nxt]);
    hipLaunchKernelGGL(lstm_gemm_cell, ggrid, gblk, 0, stream,
                       h0b[nxt], h1b[cur], 2048, Wcatr,
                       bias1r, (const float*)nullptr, (const int*)nullptr, 0, c1, h1b[nxt]);
    hipLaunchKernelGGL(fc_argmax, dim3(B / 4), dim3(256), 0, stream,
                       h1b[nxt], fcW, fcb, out, xidx, t, pred_len);
  }
}